// Round 5
// baseline (391.717 us; speedup 1.0000x reference)
//
#include <hip/hip_runtime.h>
#include <hip/hip_fp16.h>

#define BS 256
#define EPB (BS * 8)            // edges per block in deg/place kernels (8/thread)

typedef _Float16 f16x8 __attribute__((ext_vector_type(8)));
typedef float f32x4 __attribute__((ext_vector_type(4)));

// ---------------- prep: fused [mgemm1-unscaled || deg-count] ----------------
// Counting-sort graph build (r5): no more bucket/binned intermediate. Blocks
// [0,nblk) do H = fp16(X @ W1) (dinv applied per-edge in aggmm, r4-proven);
// blocks [nblk,..) histogram dst into global deg[] (16 hits/counter avg).

__global__ __launch_bounds__(BS) void k_prep(const float* __restrict__ X,
                                             const float* __restrict__ W,
                                             __half* __restrict__ H, int n,
                                             int nblk,
                                             const int* __restrict__ dst,
                                             int* __restrict__ deg, int E) {
    __shared__ __align__(16) _Float16 sB[64 * 128];
    int t = threadIdx.x;
    if (blockIdx.x >= nblk) {
        // ---- degree path ----
        int base = (blockIdx.x - nblk) * EPB;
#pragma unroll
        for (int j = 0; j < 8; ++j) {
            int e = base + j * BS + t;
            if (e < E) atomicAdd(&deg[dst[e]], 1);
        }
        return;
    }
    // ---- mgemm path: H = fp16(X @ W1), unscaled ----
    constexpr int K = 128, COLS = 64;
    constexpr int KC = K / 8;
    constexpr int SWZ = 15;
    constexpr int NT = COLS / 16;
    int bid = blockIdx.x;
    for (int idx = t; idx < COLS * KC; idx += BS) {
        int c = idx / KC, k8 = idx % KC;
        f16x8 v;
#pragma unroll
        for (int j = 0; j < 8; ++j) v[j] = (_Float16)W[(k8 * 8 + j) * COLS + c];
        *(f16x8*)&sB[c * K + ((k8 ^ (c & SWZ)) * 8)] = v;
    }
    __syncthreads();
    int w = t >> 6, lane = t & 63;
    int lm = lane & 15, q = lane >> 4;
    int row_m0 = bid * 128 + w * 32;
    f32x4 acc[2][NT];
#pragma unroll
    for (int tm = 0; tm < 2; ++tm)
#pragma unroll
        for (int tn = 0; tn < NT; ++tn) acc[tm][tn] = (f32x4){0.f, 0.f, 0.f, 0.f};
#pragma unroll
    for (int kk = 0; kk < K / 32; ++kk) {
        int k0 = kk * 32 + q * 8;
        f16x8 af[2], bf[NT];
#pragma unroll
        for (int tm = 0; tm < 2; ++tm) {
            int row = row_m0 + tm * 16 + lm;
            int rl = row < n ? row : (n - 1);  // clamp: in-bounds, values unused
            const float4* xp = (const float4*)X + ((size_t)rl * K + k0) / 4;
            float4 a = xp[0], b = xp[1];
            f16x8 v;
            v[0] = (_Float16)a.x; v[1] = (_Float16)a.y;
            v[2] = (_Float16)a.z; v[3] = (_Float16)a.w;
            v[4] = (_Float16)b.x; v[5] = (_Float16)b.y;
            v[6] = (_Float16)b.z; v[7] = (_Float16)b.w;
            af[tm] = v;
        }
#pragma unroll
        for (int tn = 0; tn < NT; ++tn) {
            int c = tn * 16 + lm;
            bf[tn] = *(const f16x8*)&sB[c * K + (((kk * 4 + q) ^ (c & SWZ)) * 8)];
        }
#pragma unroll
        for (int tm = 0; tm < 2; ++tm)
#pragma unroll
            for (int tn = 0; tn < NT; ++tn)
                acc[tm][tn] = __builtin_amdgcn_mfma_f32_16x16x32_f16(af[tm], bf[tn],
                                                                     acc[tm][tn], 0, 0, 0);
    }
#pragma unroll
    for (int tm = 0; tm < 2; ++tm) {
#pragma unroll
        for (int r = 0; r < 4; ++r) {
            int row = row_m0 + tm * 16 + q * 4 + r;
            if (row < n) {
#pragma unroll
                for (int tn = 0; tn < NT; ++tn) {
                    int col = tn * 16 + lm;
                    H[(size_t)row * COLS + col] = __float2half_rn(acc[tm][tn][r]);
                }
            }
        }
    }
}

// ---------------- scan1: per-block partial sums of (deg+1), 1024 nodes/block ----

__global__ __launch_bounds__(BS) void k_scan1(const int* __restrict__ deg,
                                              int* __restrict__ bsum, int n) {
    __shared__ int red[BS / 64];
    int b = blockIdx.x, t = threadIdx.x;
    int base = b * 1024 + t * 4;
    int s = 0;
#pragma unroll
    for (int i = 0; i < 4; ++i) {
        int v = base + i;
        if (v < n) s += deg[v] + 1;
    }
#pragma unroll
    for (int off = 32; off; off >>= 1) s += __shfl_down(s, off);
    if ((t & 63) == 0) red[t >> 6] = s;
    __syncthreads();
    if (t == 0) bsum[b] = red[0] + red[1] + red[2] + red[3];
}

// ---------------- scan2: rowptr2 / dinv / self-loop / cursors ----------------
// Every block redundantly prefixes the <=128 partials (cheap), then local scan.

__global__ __launch_bounds__(BS) void k_scan2(const int* __restrict__ deg,
                                              const int* __restrict__ bsum, int nb2,
                                              int2* __restrict__ rowptr2,
                                              float* __restrict__ dinv,
                                              int* __restrict__ csr,
                                              int* __restrict__ cur, int n) {
    __shared__ int sb[256];
    __shared__ int ws[BS / 64];
    int b = blockIdx.x, t = threadIdx.x;
    if (t < nb2) sb[t] = bsum[t];
    __syncthreads();
    int boff = 0;
    for (int q = 0; q < b; ++q) boff += sb[q];
    int base = b * 1024 + t * 4;
    int v0 = 0, v1 = 0, v2 = 0, v3 = 0;
    if (base + 0 < n) v0 = deg[base + 0] + 1;
    if (base + 1 < n) v1 = deg[base + 1] + 1;
    if (base + 2 < n) v2 = deg[base + 2] + 1;
    if (base + 3 < n) v3 = deg[base + 3] + 1;
    int tsum = v0 + v1 + v2 + v3;
    int lane = t & 63, w = t >> 6;
    int incl = tsum;
#pragma unroll
    for (int off = 1; off < 64; off <<= 1) {
        int u = __shfl_up(incl, off);
        if (lane >= off) incl += u;
    }
    if (lane == 63) ws[w] = incl;
    __syncthreads();
    int woff = 0;
    for (int q = 0; q < w; ++q) woff += ws[q];
    int st = boff + woff + incl - tsum;
    if (base + 0 < n) {
        rowptr2[base + 0] = make_int2(st, st + v0);
        dinv[base + 0] = rsqrtf((float)v0);
        csr[st] = base + 0;
        cur[base + 0] = st + 1;
    }
    st += v0;
    if (base + 1 < n) {
        rowptr2[base + 1] = make_int2(st, st + v1);
        dinv[base + 1] = rsqrtf((float)v1);
        csr[st] = base + 1;
        cur[base + 1] = st + 1;
    }
    st += v1;
    if (base + 2 < n) {
        rowptr2[base + 2] = make_int2(st, st + v2);
        dinv[base + 2] = rsqrtf((float)v2);
        csr[st] = base + 2;
        cur[base + 2] = st + 1;
    }
    st += v2;
    if (base + 3 < n) {
        rowptr2[base + 3] = make_int2(st, st + v3);
        dinv[base + 3] = rsqrtf((float)v3);
        csr[st] = base + 3;
        cur[base + 3] = st + 1;
    }
}

// ---------------- place: csr[atomic cursor(dst)] = src ----------------
// Streamed edge read; random 4B writes into 6.8MB csr (L2/LLC-absorbed);
// 1.6M atomics over 100K cursors (400KB, L2-resident, ~16/counter).

__global__ __launch_bounds__(BS) void k_place(const int* __restrict__ src,
                                              const int* __restrict__ dst,
                                              int* __restrict__ cur,
                                              int* __restrict__ csr, int E) {
    int t = threadIdx.x;
    int base = blockIdx.x * EPB;
#pragma unroll
    for (int j = 0; j < 8; ++j) {
        int e = base + j * BS + t;
        if (e < E) {
            int pos = atomicAdd(&cur[dst[e]], 1);
            csr[pos] = src[e];
        }
    }
}

// ---------------- aggmm: fused agg64 + relu(v+b1) + (u @ W2) * dinv -> h2 fp16 ------
// r4-proven: per-edge dinv[src] fused via __hfma2; lean loop (staging null, r3).
// Pinned ~56us at the random-line fabric service floor (~1.7TB/s on 86MB).

__device__ __forceinline__ void acc_fma(float4 raw, __half2 d, __half2& p0, __half2& p1,
                                        __half2& p2, __half2& p3) {
    const __half2* u = (const __half2*)&raw;
    p0 = __hfma2(u[0], d, p0); p1 = __hfma2(u[1], d, p1);
    p2 = __hfma2(u[2], d, p2); p3 = __hfma2(u[3], d, p3);
}

__global__ __launch_bounds__(BS) void k_aggmm(const __half* __restrict__ hsrc,
                                              const int* __restrict__ csr,
                                              const int2* __restrict__ rowptr2,
                                              const float* __restrict__ dinv,
                                              const float* __restrict__ b1,
                                              const float* __restrict__ W2,  // [64][32]
                                              __half* __restrict__ h2, int n) {
    __shared__ float sW2[64 * 32];            // 8 KB, layout [k][c]
    __shared__ float sB1[64];
    __shared__ float sU[(BS / 64) * 2 * 64];  // 4 waves x 2 nodes x 64 = 2 KB
    int t = threadIdx.x;
    for (int i = t; i < 64 * 32; i += BS) sW2[i] = W2[i];
    if (t < 64) sB1[t] = b1[t];
    __syncthreads();

    int npairs = (n + 1) / 2;
    int wib = t >> 6;
    int wid = blockIdx.x * (BS / 64) + wib;
    if (wid >= npairs) return;  // wave-uniform; no barriers after this point
    int lane = t & 63;
    int half = lane >> 5, hl = lane & 31;
    int node = wid * 2 + half;
    bool valid = node < n;
    int b = 0, e = 0;
    if (valid) { int2 be = rowptr2[node]; b = be.x; e = be.y; }
    int slot = hl >> 3, fq = hl & 7;  // 4 edge slots, feature octet fq*8..fq*8+8
    __half2 pA0 = __float2half2_rn(0.f), pA1 = pA0, pA2 = pA0, pA3 = pA0;
    __half2 pB0 = pA0, pB1 = pA0, pB2 = pA0, pB3 = pA0;
    for (int c = b; c < e; c += 32) {
        int m = e - c;
        if (m > 32) m = 32;
        int sv = (hl < m) ? csr[c + hl] : 0;
        float dsv = dinv[sv];  // lanes hl>=m load dinv[0]; never selected below
        int j = 0;
        for (; j + 7 < m; j += 8) {
            int s0 = __shfl(sv, j + slot, 32);
            float d0 = __shfl(dsv, j + slot, 32);
            int s1 = __shfl(sv, j + 4 + slot, 32);
            float d1 = __shfl(dsv, j + 4 + slot, 32);
            float4 r0 = *((const float4*)(hsrc + (size_t)s0 * 64) + fq);
            float4 r1 = *((const float4*)(hsrc + (size_t)s1 * 64) + fq);
            acc_fma(r0, __float2half2_rn(d0), pA0, pA1, pA2, pA3);
            acc_fma(r1, __float2half2_rn(d1), pB0, pB1, pB2, pB3);
        }
        for (; j < m; j += 4) {
            int js = j + slot;
            int s = __shfl(sv, js < m ? js : 0, 32);
            float d = __shfl(dsv, js < m ? js : 0, 32);
            if (js < m) {
                float4 r0 = *((const float4*)(hsrc + (size_t)s * 64) + fq);
                acc_fma(r0, __float2half2_rn(d), pA0, pA1, pA2, pA3);
            }
        }
    }
    // merge packed partials in fp32: 8 feature sums per lane
    float2 f0 = __half22float2(pA0), f1 = __half22float2(pA1);
    float2 f2 = __half22float2(pA2), f3 = __half22float2(pA3);
    float2 g0 = __half22float2(pB0), g1v = __half22float2(pB1);
    float2 g2 = __half22float2(pB2), g3 = __half22float2(pB3);
    float a0 = f0.x + g0.x, a1 = f0.y + g0.y, a2 = f1.x + g1v.x, a3 = f1.y + g1v.y;
    float a4 = f2.x + g2.x, a5 = f2.y + g2.y, a6 = f3.x + g3.x, a7 = f3.y + g3.y;
    // cross-slot reduction: slots {0,1,2,3} at hl = slot*8+fq
    a0 += __shfl_down(a0, 16); a1 += __shfl_down(a1, 16);
    a2 += __shfl_down(a2, 16); a3 += __shfl_down(a3, 16);
    a4 += __shfl_down(a4, 16); a5 += __shfl_down(a5, 16);
    a6 += __shfl_down(a6, 16); a7 += __shfl_down(a7, 16);
    a0 += __shfl_down(a0, 8);  a1 += __shfl_down(a1, 8);
    a2 += __shfl_down(a2, 8);  a3 += __shfl_down(a3, 8);
    a4 += __shfl_down(a4, 8);  a5 += __shfl_down(a5, 8);
    a6 += __shfl_down(a6, 8);  a7 += __shfl_down(a7, 8);

    // layer-2 input: u = relu(dinv[node] * acc + b1); lanes hl<8 own features hl*8..+8
    if (valid && hl < 8) {
        float dv = dinv[node];
        float* up = &sU[(wib * 2 + half) * 64 + hl * 8];
        up[0] = fmaxf(a0 * dv + sB1[hl * 8 + 0], 0.f);
        up[1] = fmaxf(a1 * dv + sB1[hl * 8 + 1], 0.f);
        up[2] = fmaxf(a2 * dv + sB1[hl * 8 + 2], 0.f);
        up[3] = fmaxf(a3 * dv + sB1[hl * 8 + 3], 0.f);
        up[4] = fmaxf(a4 * dv + sB1[hl * 8 + 4], 0.f);
        up[5] = fmaxf(a5 * dv + sB1[hl * 8 + 5], 0.f);
        up[6] = fmaxf(a6 * dv + sB1[hl * 8 + 6], 0.f);
        up[7] = fmaxf(a7 * dv + sB1[hl * 8 + 7], 0.f);
    }
    // in-wave matvec: lanes 0-31 -> node A cols, lanes 32-63 -> node B cols.
    int nodeSel = lane >> 5;
    int mvnode = wid * 2 + nodeSel;
    if (mvnode < n) {
        const float* u = &sU[(wib * 2 + nodeSel) * 64];
        int cc = lane & 31;
        float acc = 0.f;
#pragma unroll
        for (int k = 0; k < 64; ++k) acc = fmaf(u[k], sW2[k * 32 + cc], acc);
        h2[(size_t)mvnode * 32 + cc] = __float2half_rn(acc * dinv[mvnode]);
    }
}

// ---------------- agg32: out = dinv .* (A-gather h2) + b2 (fp32) ----------------
// 4 lanes/edge x float4 (full 64B row), 8 edge slots per half, fp32 accumulate.
// h2 rows already carry their src-side dinv (folded in aggmm's h2 write).

__global__ __launch_bounds__(BS) void k_agg32(const __half* __restrict__ h,
                                              const int* __restrict__ csr,
                                              const int2* __restrict__ rowptr2,
                                              const float* __restrict__ dinv,
                                              const float* __restrict__ bias,
                                              float* __restrict__ out, int n) {
    int wid = (blockIdx.x * BS + threadIdx.x) >> 6;
    int lane = threadIdx.x & 63;
    int half = lane >> 5, hl = lane & 31;
    int node = wid * 2 + half;
    bool valid = node < n;
    int b = 0, e = 0;
    if (valid) { int2 be = rowptr2[node]; b = be.x; e = be.y; }
    int slot = hl >> 2, fq = hl & 3;  // 8 edge slots, feature quad fq*8..fq*8+8
    float a0 = 0.f, a1 = 0.f, a2 = 0.f, a3 = 0.f;
    float a4 = 0.f, a5 = 0.f, a6 = 0.f, a7 = 0.f;
    for (int c = b; c < e; c += 32) {
        int m = e - c;
        if (m > 32) m = 32;
        int sv = (hl < m) ? csr[c + hl] : 0;
        int j = 0;
        for (; j + 15 < m; j += 16) {
            int s0 = __shfl(sv, j + slot, 32);
            int s1 = __shfl(sv, j + 8 + slot, 32);
            float4 r0 = *((const float4*)(h + (size_t)s0 * 32) + fq);
            float4 r1 = *((const float4*)(h + (size_t)s1 * 32) + fq);
            const __half2* u0 = (const __half2*)&r0;
            const __half2* u1 = (const __half2*)&r1;
            float2 q0 = __half22float2(u0[0]), q1 = __half22float2(u0[1]);
            float2 q2 = __half22float2(u0[2]), q3 = __half22float2(u0[3]);
            a0 += q0.x; a1 += q0.y; a2 += q1.x; a3 += q1.y;
            a4 += q2.x; a5 += q2.y; a6 += q3.x; a7 += q3.y;
            q0 = __half22float2(u1[0]); q1 = __half22float2(u1[1]);
            q2 = __half22float2(u1[2]); q3 = __half22float2(u1[3]);
            a0 += q0.x; a1 += q0.y; a2 += q1.x; a3 += q1.y;
            a4 += q2.x; a5 += q2.y; a6 += q3.x; a7 += q3.y;
        }
        for (; j < m; j += 8) {
            int js = j + slot;
            int s = __shfl(sv, js < m ? js : 0, 32);
            if (js < m) {
                float4 r0 = *((const float4*)(h + (size_t)s * 32) + fq);
                const __half2* u0 = (const __half2*)&r0;
                float2 q0 = __half22float2(u0[0]), q1 = __half22float2(u0[1]);
                float2 q2 = __half22float2(u0[2]), q3 = __half22float2(u0[3]);
                a0 += q0.x; a1 += q0.y; a2 += q1.x; a3 += q1.y;
                a4 += q2.x; a5 += q2.y; a6 += q3.x; a7 += q3.y;
            }
        }
    }
    // cross-slot reduction: slots {0..7} at hl = slot*4+fq
    a0 += __shfl_down(a0, 16); a1 += __shfl_down(a1, 16);
    a2 += __shfl_down(a2, 16); a3 += __shfl_down(a3, 16);
    a4 += __shfl_down(a4, 16); a5 += __shfl_down(a5, 16);
    a6 += __shfl_down(a6, 16); a7 += __shfl_down(a7, 16);
    a0 += __shfl_down(a0, 8);  a1 += __shfl_down(a1, 8);
    a2 += __shfl_down(a2, 8);  a3 += __shfl_down(a3, 8);
    a4 += __shfl_down(a4, 8);  a5 += __shfl_down(a5, 8);
    a6 += __shfl_down(a6, 8);  a7 += __shfl_down(a7, 8);
    a0 += __shfl_down(a0, 4);  a1 += __shfl_down(a1, 4);
    a2 += __shfl_down(a2, 4);  a3 += __shfl_down(a3, 4);
    a4 += __shfl_down(a4, 4);  a5 += __shfl_down(a5, 4);
    a6 += __shfl_down(a6, 4);  a7 += __shfl_down(a7, 4);
    if (valid && hl < 4) {
        float dv = dinv[node];
        const float4* bp = (const float4*)bias + hl * 2;
        float4 b0 = bp[0], b1v = bp[1];
        float4 o0 = make_float4(a0 * dv + b0.x, a1 * dv + b0.y,
                                a2 * dv + b0.z, a3 * dv + b0.w);
        float4 o1 = make_float4(a4 * dv + b1v.x, a5 * dv + b1v.y,
                                a6 * dv + b1v.z, a7 * dv + b1v.w);
        float4* op = (float4*)(out + (size_t)node * 32 + hl * 8);
        op[0] = o0; op[1] = o1;
    }
}

// ---------------- launch ----------------

extern "C" void kernel_launch(void* const* d_in, const int* in_sizes, int n_in,
                              void* d_out, int out_size, void* d_ws, size_t ws_size,
                              hipStream_t stream) {
    const float* x  = (const float*)d_in[0];
    const int* eidx = (const int*)d_in[1];
    const float* W1 = (const float*)d_in[2];
    const float* b1 = (const float*)d_in[3];
    const float* W2 = (const float*)d_in[4];
    const float* b2 = (const float*)d_in[5];
    float* out = (float*)d_out;

    int n = in_sizes[0] / 128;
    int E = in_sizes[1] / 2;
    const int* srcA = eidx;
    const int* dstA = eidx + E;

    char* p = (char*)d_ws;
    auto alloc = [&](size_t bytes) {
        char* q = p;
        p += (bytes + 255) & ~(size_t)255;
        return q;
    };
    int2*   rowptr2 = (int2*)alloc((size_t)n * 8);
    float*  dinv    = (float*)alloc((size_t)n * 4);
    int*    deg     = (int*)alloc((size_t)n * 4);
    int*    cur     = (int*)alloc((size_t)n * 4);
    int*    bsum    = (int*)alloc(256 * 4);
    int*    csr     = (int*)alloc(((size_t)E + n + 256) * 4);
    __half* h1      = (__half*)alloc((size_t)n * 64 * 2);
    __half* h2      = (__half*)alloc((size_t)n * 32 * 2);

    int nblk   = (n + 127) / 128;              // 782 mgemm blocks
    int dblk   = (E + EPB - 1) / EPB;          // 782 deg/place blocks
    int nb2    = (n + 1023) / 1024;            // 98 scan blocks
    int npairs = (n + 1) / 2;                  // 2 nodes per wave
    int aggblk = (npairs + (BS / 64) - 1) / (BS / 64);

    hipMemsetAsync(deg, 0, (size_t)n * 4, stream);
    k_prep<<<nblk + dblk, BS, 0, stream>>>(x, W1, h1, n, nblk, dstA, deg, E);
    k_scan1<<<nb2, BS, 0, stream>>>(deg, bsum, n);
    k_scan2<<<nb2, BS, 0, stream>>>(deg, bsum, nb2, rowptr2, dinv, csr, cur, n);
    k_place<<<dblk, BS, 0, stream>>>(srcA, dstA, cur, csr, E);
    k_aggmm<<<aggblk, BS, 0, stream>>>(h1, csr, rowptr2, dinv, b1, W2, h2, n);
    k_agg32<<<aggblk, BS, 0, stream>>>(h2, csr, rowptr2, dinv, b2, out, n);
}

// Round 6
// 308.545 us; speedup vs baseline: 1.2696x; 1.2696x over previous
//
#include <hip/hip_runtime.h>
#include <hip/hip_fp16.h>

#define BS 256
#define BSHIFT 9                // 512 nodes per bucket
#define BNODES (1 << BSHIFT)
#define NBKT 256                // bucket table size (>= ceil(100000/512)=196); n <= 2^17
#define CAP 12288               // edge capacity per bucket (mean 8192 at E=1.6M, +45 sigma)
#define CHUNK 4096              // edges per scatter chunk (16/thread)
#define PB 4                    // place blocks per bucket (784 total)
// packed edge word: src in bits [0,17), local dst (li) in bits [17,26)

typedef _Float16 f16x8 __attribute__((ext_vector_type(8)));
typedef float f32x4 __attribute__((ext_vector_type(4)));

// ---------------- prep: fused [scatter+deg || mgemm1-unscaled] ----------------
// r6: scatter blocks also count deg[dst] (global atomics, L2-resident, proven
// cheap in r5) — this deletes k_build's histogram pass over binned entirely.
// csr layout/cursors come from the tiny scan kernels; placement from k_place2.

__global__ __launch_bounds__(BS) void k_prep(const int* __restrict__ src,
                                             const int* __restrict__ dst,
                                             int* __restrict__ gcursor,
                                             int* __restrict__ binned,
                                             int* __restrict__ deg, int E,
                                             const float* __restrict__ X,
                                             const float* __restrict__ W,
                                             __half* __restrict__ H, int n,
                                             int nchunks) {
    __shared__ int sh[NBKT];
    __shared__ int sbase[NBKT];
    __shared__ __align__(16) _Float16 sB[64 * 128];
    int t = threadIdx.x;
    if (blockIdx.x < nchunks) {
        // ---- scatter + deg path ----
        sh[t] = 0;
        __syncthreads();
        int cbase = blockIdx.x * CHUNK;
        int sv[CHUNK / BS], dv[CHUNK / BS], rv[CHUNK / BS];
#pragma unroll
        for (int j = 0; j < CHUNK / BS; ++j) {
            int e = cbase + j * BS + t;
            rv[j] = -1;
            if (e < E) {
                sv[j] = src[e];
                dv[j] = dst[e];
                rv[j] = atomicAdd(&sh[dv[j] >> BSHIFT], 1);
                atomicAdd(&deg[dv[j]], 1);
            }
        }
        __syncthreads();
        sbase[t] = sh[t] ? atomicAdd(&gcursor[t], sh[t]) : 0;
        __syncthreads();
#pragma unroll
        for (int j = 0; j < CHUNK / BS; ++j) {
            if (rv[j] >= 0) {
                int b = dv[j] >> BSHIFT;
                binned[(size_t)b * CAP + sbase[b] + rv[j]] =
                    sv[j] | ((dv[j] & (BNODES - 1)) << 17);
            }
        }
        return;
    }
    // ---- mgemm path: H = fp16(X @ W1), unscaled (dinv per-edge in aggmm, r4) ----
    constexpr int K = 128, COLS = 64;
    constexpr int KC = K / 8;
    constexpr int SWZ = 15;
    constexpr int NT = COLS / 16;
    int bid = blockIdx.x - nchunks;
    for (int idx = t; idx < COLS * KC; idx += BS) {
        int c = idx / KC, k8 = idx % KC;
        f16x8 v;
#pragma unroll
        for (int j = 0; j < 8; ++j) v[j] = (_Float16)W[(k8 * 8 + j) * COLS + c];
        *(f16x8*)&sB[c * K + ((k8 ^ (c & SWZ)) * 8)] = v;
    }
    __syncthreads();
    int w = t >> 6, lane = t & 63;
    int lm = lane & 15, q = lane >> 4;
    int row_m0 = bid * 128 + w * 32;
    f32x4 acc[2][NT];
#pragma unroll
    for (int tm = 0; tm < 2; ++tm)
#pragma unroll
        for (int tn = 0; tn < NT; ++tn) acc[tm][tn] = (f32x4){0.f, 0.f, 0.f, 0.f};
#pragma unroll
    for (int kk = 0; kk < K / 32; ++kk) {
        int k0 = kk * 32 + q * 8;
        f16x8 af[2], bf[NT];
#pragma unroll
        for (int tm = 0; tm < 2; ++tm) {
            int row = row_m0 + tm * 16 + lm;
            int rl = row < n ? row : (n - 1);  // clamp: in-bounds, values unused
            const float4* xp = (const float4*)X + ((size_t)rl * K + k0) / 4;
            float4 a = xp[0], b = xp[1];
            f16x8 v;
            v[0] = (_Float16)a.x; v[1] = (_Float16)a.y;
            v[2] = (_Float16)a.z; v[3] = (_Float16)a.w;
            v[4] = (_Float16)b.x; v[5] = (_Float16)b.y;
            v[6] = (_Float16)b.z; v[7] = (_Float16)b.w;
            af[tm] = v;
        }
#pragma unroll
        for (int tn = 0; tn < NT; ++tn) {
            int c = tn * 16 + lm;
            bf[tn] = *(const f16x8*)&sB[c * K + (((kk * 4 + q) ^ (c & SWZ)) * 8)];
        }
#pragma unroll
        for (int tm = 0; tm < 2; ++tm)
#pragma unroll
            for (int tn = 0; tn < NT; ++tn)
                acc[tm][tn] = __builtin_amdgcn_mfma_f32_16x16x32_f16(af[tm], bf[tn],
                                                                     acc[tm][tn], 0, 0, 0);
    }
#pragma unroll
    for (int tm = 0; tm < 2; ++tm) {
#pragma unroll
        for (int r = 0; r < 4; ++r) {
            int row = row_m0 + tm * 16 + q * 4 + r;
            if (row < n) {
#pragma unroll
                for (int tn = 0; tn < NT; ++tn) {
                    int col = tn * 16 + lm;
                    H[(size_t)row * COLS + col] = __float2half_rn(acc[tm][tn][r]);
                }
            }
        }
    }
}

// ---------------- scan1: per-block partial sums of (deg+1), 1024 nodes/block ----

__global__ __launch_bounds__(BS) void k_scan1(const int* __restrict__ deg,
                                              int* __restrict__ bsum, int n) {
    __shared__ int red[BS / 64];
    int b = blockIdx.x, t = threadIdx.x;
    int base = b * 1024 + t * 4;
    int s = 0;
#pragma unroll
    for (int i = 0; i < 4; ++i) {
        int v = base + i;
        if (v < n) s += deg[v] + 1;
    }
#pragma unroll
    for (int off = 32; off; off >>= 1) s += __shfl_down(s, off);
    if ((t & 63) == 0) red[t >> 6] = s;
    __syncthreads();
    if (t == 0) bsum[b] = red[0] + red[1] + red[2] + red[3];
}

// ---------------- scan2: rowptr2 / dinv / self-loop / cursors (r5-verified) ----

__global__ __launch_bounds__(BS) void k_scan2(const int* __restrict__ deg,
                                              const int* __restrict__ bsum, int nb2,
                                              int2* __restrict__ rowptr2,
                                              float* __restrict__ dinv,
                                              int* __restrict__ csr,
                                              int* __restrict__ cur, int n) {
    __shared__ int sb[256];
    __shared__ int ws[BS / 64];
    int b = blockIdx.x, t = threadIdx.x;
    if (t < nb2) sb[t] = bsum[t];
    __syncthreads();
    int boff = 0;
    for (int q = 0; q < b; ++q) boff += sb[q];
    int base = b * 1024 + t * 4;
    int v0 = 0, v1 = 0, v2 = 0, v3 = 0;
    if (base + 0 < n) v0 = deg[base + 0] + 1;
    if (base + 1 < n) v1 = deg[base + 1] + 1;
    if (base + 2 < n) v2 = deg[base + 2] + 1;
    if (base + 3 < n) v3 = deg[base + 3] + 1;
    int tsum = v0 + v1 + v2 + v3;
    int lane = t & 63, w = t >> 6;
    int incl = tsum;
#pragma unroll
    for (int off = 1; off < 64; off <<= 1) {
        int u = __shfl_up(incl, off);
        if (lane >= off) incl += u;
    }
    if (lane == 63) ws[w] = incl;
    __syncthreads();
    int woff = 0;
    for (int q = 0; q < w; ++q) woff += ws[q];
    int st = boff + woff + incl - tsum;
    if (base + 0 < n) {
        rowptr2[base + 0] = make_int2(st, st + v0);
        dinv[base + 0] = rsqrtf((float)v0);
        csr[st] = base + 0;
        cur[base + 0] = st + 1;
    }
    st += v0;
    if (base + 1 < n) {
        rowptr2[base + 1] = make_int2(st, st + v1);
        dinv[base + 1] = rsqrtf((float)v1);
        csr[st] = base + 1;
        cur[base + 1] = st + 1;
    }
    st += v1;
    if (base + 2 < n) {
        rowptr2[base + 2] = make_int2(st, st + v2);
        dinv[base + 2] = rsqrtf((float)v2);
        csr[st] = base + 2;
        cur[base + 2] = st + 1;
    }
    st += v2;
    if (base + 3 < n) {
        rowptr2[base + 3] = make_int2(st, st + v3);
        dinv[base + 3] = rsqrtf((float)v3);
        csr[st] = base + 3;
        cur[base + 3] = st + 1;
    }
}

// ---------------- place2: bucket-local csr fill, 4 blocks/bucket ----------------
// Reads the bucket's binned slice (sequential); global cur atomics (400KB,
// L2-resident); csr writes land in the bucket's contiguous ~70KB region —
// many writes per line, NO 64B write amplification (the r5 k_place failure).

__global__ __launch_bounds__(BS) void k_place2(const int* __restrict__ binned,
                                               const int* __restrict__ cnts,
                                               int* __restrict__ cur,
                                               int* __restrict__ csr) {
    int bkt = blockIdx.x / PB, sl = blockIdx.x % PB;
    int cnt = cnts[bkt];
    const int* eb = binned + (size_t)bkt * CAP;
    int node0 = bkt << BSHIFT;
    for (int e = sl * BS + threadIdx.x; e < cnt; e += PB * BS) {
        int p = eb[e];
        int node = node0 + (p >> 17);
        int pos = atomicAdd(&cur[node], 1);
        csr[pos] = p & 0x1FFFF;
    }
}

// ---------------- aggmm: fused agg64 + relu(v+b1) + (u @ W2) * dinv -> h2 fp16 ------
// FROZEN (r4-proven): per-edge dinv[src] via __hfma2; lean loop. Pinned ~56us at
// the random-line fabric service floor (~1.7TB/s on 86MB; invariant r9/r13/r14/r3).

__device__ __forceinline__ void acc_fma(float4 raw, __half2 d, __half2& p0, __half2& p1,
                                        __half2& p2, __half2& p3) {
    const __half2* u = (const __half2*)&raw;
    p0 = __hfma2(u[0], d, p0); p1 = __hfma2(u[1], d, p1);
    p2 = __hfma2(u[2], d, p2); p3 = __hfma2(u[3], d, p3);
}

__global__ __launch_bounds__(BS) void k_aggmm(const __half* __restrict__ hsrc,
                                              const int* __restrict__ csr,
                                              const int2* __restrict__ rowptr2,
                                              const float* __restrict__ dinv,
                                              const float* __restrict__ b1,
                                              const float* __restrict__ W2,  // [64][32]
                                              __half* __restrict__ h2, int n) {
    __shared__ float sW2[64 * 32];            // 8 KB, layout [k][c]
    __shared__ float sB1[64];
    __shared__ float sU[(BS / 64) * 2 * 64];  // 4 waves x 2 nodes x 64 = 2 KB
    int t = threadIdx.x;
    for (int i = t; i < 64 * 32; i += BS) sW2[i] = W2[i];
    if (t < 64) sB1[t] = b1[t];
    __syncthreads();

    int npairs = (n + 1) / 2;
    int wib = t >> 6;
    int wid = blockIdx.x * (BS / 64) + wib;
    if (wid >= npairs) return;  // wave-uniform; no barriers after this point
    int lane = t & 63;
    int half = lane >> 5, hl = lane & 31;
    int node = wid * 2 + half;
    bool valid = node < n;
    int b = 0, e = 0;
    if (valid) { int2 be = rowptr2[node]; b = be.x; e = be.y; }
    int slot = hl >> 3, fq = hl & 7;  // 4 edge slots, feature octet fq*8..fq*8+8
    __half2 pA0 = __float2half2_rn(0.f), pA1 = pA0, pA2 = pA0, pA3 = pA0;
    __half2 pB0 = pA0, pB1 = pA0, pB2 = pA0, pB3 = pA0;
    for (int c = b; c < e; c += 32) {
        int m = e - c;
        if (m > 32) m = 32;
        int sv = (hl < m) ? csr[c + hl] : 0;
        float dsv = dinv[sv];  // lanes hl>=m load dinv[0]; never selected below
        int j = 0;
        for (; j + 7 < m; j += 8) {
            int s0 = __shfl(sv, j + slot, 32);
            float d0 = __shfl(dsv, j + slot, 32);
            int s1 = __shfl(sv, j + 4 + slot, 32);
            float d1 = __shfl(dsv, j + 4 + slot, 32);
            float4 r0 = *((const float4*)(hsrc + (size_t)s0 * 64) + fq);
            float4 r1 = *((const float4*)(hsrc + (size_t)s1 * 64) + fq);
            acc_fma(r0, __float2half2_rn(d0), pA0, pA1, pA2, pA3);
            acc_fma(r1, __float2half2_rn(d1), pB0, pB1, pB2, pB3);
        }
        for (; j < m; j += 4) {
            int js = j + slot;
            int s = __shfl(sv, js < m ? js : 0, 32);
            float d = __shfl(dsv, js < m ? js : 0, 32);
            if (js < m) {
                float4 r0 = *((const float4*)(hsrc + (size_t)s * 64) + fq);
                acc_fma(r0, __float2half2_rn(d), pA0, pA1, pA2, pA3);
            }
        }
    }
    // merge packed partials in fp32: 8 feature sums per lane
    float2 f0 = __half22float2(pA0), f1 = __half22float2(pA1);
    float2 f2 = __half22float2(pA2), f3 = __half22float2(pA3);
    float2 g0 = __half22float2(pB0), g1v = __half22float2(pB1);
    float2 g2 = __half22float2(pB2), g3 = __half22float2(pB3);
    float a0 = f0.x + g0.x, a1 = f0.y + g0.y, a2 = f1.x + g1v.x, a3 = f1.y + g1v.y;
    float a4 = f2.x + g2.x, a5 = f2.y + g2.y, a6 = f3.x + g3.x, a7 = f3.y + g3.y;
    // cross-slot reduction: slots {0,1,2,3} at hl = slot*8+fq
    a0 += __shfl_down(a0, 16); a1 += __shfl_down(a1, 16);
    a2 += __shfl_down(a2, 16); a3 += __shfl_down(a3, 16);
    a4 += __shfl_down(a4, 16); a5 += __shfl_down(a5, 16);
    a6 += __shfl_down(a6, 16); a7 += __shfl_down(a7, 16);
    a0 += __shfl_down(a0, 8);  a1 += __shfl_down(a1, 8);
    a2 += __shfl_down(a2, 8);  a3 += __shfl_down(a3, 8);
    a4 += __shfl_down(a4, 8);  a5 += __shfl_down(a5, 8);
    a6 += __shfl_down(a6, 8);  a7 += __shfl_down(a7, 8);

    // layer-2 input: u = relu(dinv[node] * acc + b1); lanes hl<8 own features hl*8..+8
    if (valid && hl < 8) {
        float dv = dinv[node];
        float* up = &sU[(wib * 2 + half) * 64 + hl * 8];
        up[0] = fmaxf(a0 * dv + sB1[hl * 8 + 0], 0.f);
        up[1] = fmaxf(a1 * dv + sB1[hl * 8 + 1], 0.f);
        up[2] = fmaxf(a2 * dv + sB1[hl * 8 + 2], 0.f);
        up[3] = fmaxf(a3 * dv + sB1[hl * 8 + 3], 0.f);
        up[4] = fmaxf(a4 * dv + sB1[hl * 8 + 4], 0.f);
        up[5] = fmaxf(a5 * dv + sB1[hl * 8 + 5], 0.f);
        up[6] = fmaxf(a6 * dv + sB1[hl * 8 + 6], 0.f);
        up[7] = fmaxf(a7 * dv + sB1[hl * 8 + 7], 0.f);
    }
    // in-wave matvec: lanes 0-31 -> node A cols, lanes 32-63 -> node B cols.
    int nodeSel = lane >> 5;
    int mvnode = wid * 2 + nodeSel;
    if (mvnode < n) {
        const float* u = &sU[(wib * 2 + nodeSel) * 64];
        int cc = lane & 31;
        float acc = 0.f;
#pragma unroll
        for (int k = 0; k < 64; ++k) acc = fmaf(u[k], sW2[k * 32 + cc], acc);
        h2[(size_t)mvnode * 32 + cc] = __float2half_rn(acc * dinv[mvnode]);
    }
}

// ---------------- agg32: out = dinv .* (A-gather h2) + b2 (fp32) ----------------
// 4 lanes/edge x float4 (full 64B row), 8 edge slots per half, fp32 accumulate.
// h2 rows already carry their src-side dinv (folded in aggmm's h2 write).

__global__ __launch_bounds__(BS) void k_agg32(const __half* __restrict__ h,
                                              const int* __restrict__ csr,
                                              const int2* __restrict__ rowptr2,
                                              const float* __restrict__ dinv,
                                              const float* __restrict__ bias,
                                              float* __restrict__ out, int n) {
    int wid = (blockIdx.x * BS + threadIdx.x) >> 6;
    int lane = threadIdx.x & 63;
    int half = lane >> 5, hl = lane & 31;
    int node = wid * 2 + half;
    bool valid = node < n;
    int b = 0, e = 0;
    if (valid) { int2 be = rowptr2[node]; b = be.x; e = be.y; }
    int slot = hl >> 2, fq = hl & 3;  // 8 edge slots, feature quad fq*8..fq*8+8
    float a0 = 0.f, a1 = 0.f, a2 = 0.f, a3 = 0.f;
    float a4 = 0.f, a5 = 0.f, a6 = 0.f, a7 = 0.f;
    for (int c = b; c < e; c += 32) {
        int m = e - c;
        if (m > 32) m = 32;
        int sv = (hl < m) ? csr[c + hl] : 0;
        int j = 0;
        for (; j + 15 < m; j += 16) {
            int s0 = __shfl(sv, j + slot, 32);
            int s1 = __shfl(sv, j + 8 + slot, 32);
            float4 r0 = *((const float4*)(h + (size_t)s0 * 32) + fq);
            float4 r1 = *((const float4*)(h + (size_t)s1 * 32) + fq);
            const __half2* u0 = (const __half2*)&r0;
            const __half2* u1 = (const __half2*)&r1;
            float2 q0 = __half22float2(u0[0]), q1 = __half22float2(u0[1]);
            float2 q2 = __half22float2(u0[2]), q3 = __half22float2(u0[3]);
            a0 += q0.x; a1 += q0.y; a2 += q1.x; a3 += q1.y;
            a4 += q2.x; a5 += q2.y; a6 += q3.x; a7 += q3.y;
            q0 = __half22float2(u1[0]); q1 = __half22float2(u1[1]);
            q2 = __half22float2(u1[2]); q3 = __half22float2(u1[3]);
            a0 += q0.x; a1 += q0.y; a2 += q1.x; a3 += q1.y;
            a4 += q2.x; a5 += q2.y; a6 += q3.x; a7 += q3.y;
        }
        for (; j < m; j += 8) {
            int js = j + slot;
            int s = __shfl(sv, js < m ? js : 0, 32);
            if (js < m) {
                float4 r0 = *((const float4*)(h + (size_t)s * 32) + fq);
                const __half2* u0 = (const __half2*)&r0;
                float2 q0 = __half22float2(u0[0]), q1 = __half22float2(u0[1]);
                float2 q2 = __half22float2(u0[2]), q3 = __half22float2(u0[3]);
                a0 += q0.x; a1 += q0.y; a2 += q1.x; a3 += q1.y;
                a4 += q2.x; a5 += q2.y; a6 += q3.x; a7 += q3.y;
            }
        }
    }
    // cross-slot reduction: slots {0..7} at hl = slot*4+fq
    a0 += __shfl_down(a0, 16); a1 += __shfl_down(a1, 16);
    a2 += __shfl_down(a2, 16); a3 += __shfl_down(a3, 16);
    a4 += __shfl_down(a4, 16); a5 += __shfl_down(a5, 16);
    a6 += __shfl_down(a6, 16); a7 += __shfl_down(a7, 16);
    a0 += __shfl_down(a0, 8);  a1 += __shfl_down(a1, 8);
    a2 += __shfl_down(a2, 8);  a3 += __shfl_down(a3, 8);
    a4 += __shfl_down(a4, 8);  a5 += __shfl_down(a5, 8);
    a6 += __shfl_down(a6, 8);  a7 += __shfl_down(a7, 8);
    a0 += __shfl_down(a0, 4);  a1 += __shfl_down(a1, 4);
    a2 += __shfl_down(a2, 4);  a3 += __shfl_down(a3, 4);
    a4 += __shfl_down(a4, 4);  a5 += __shfl_down(a5, 4);
    a6 += __shfl_down(a6, 4);  a7 += __shfl_down(a7, 4);
    if (valid && hl < 4) {
        float dv = dinv[node];
        const float4* bp = (const float4*)bias + hl * 2;
        float4 b0 = bp[0], b1v = bp[1];
        float4 o0 = make_float4(a0 * dv + b0.x, a1 * dv + b0.y,
                                a2 * dv + b0.z, a3 * dv + b0.w);
        float4 o1 = make_float4(a4 * dv + b1v.x, a5 * dv + b1v.y,
                                a6 * dv + b1v.z, a7 * dv + b1v.w);
        float4* op = (float4*)(out + (size_t)node * 32 + hl * 8);
        op[0] = o0; op[1] = o1;
    }
}

// ---------------- launch ----------------

extern "C" void kernel_launch(void* const* d_in, const int* in_sizes, int n_in,
                              void* d_out, int out_size, void* d_ws, size_t ws_size,
                              hipStream_t stream) {
    const float* x  = (const float*)d_in[0];
    const int* eidx = (const int*)d_in[1];
    const float* W1 = (const float*)d_in[2];
    const float* b1 = (const float*)d_in[3];
    const float* W2 = (const float*)d_in[4];
    const float* b2 = (const float*)d_in[5];
    float* out = (float*)d_out;

    int n = in_sizes[0] / 128;
    int E = in_sizes[1] / 2;
    const int* srcA = eidx;
    const int* dstA = eidx + E;

    char* p = (char*)d_ws;
    auto alloc = [&](size_t bytes) {
        char* q = p;
        p += (bytes + 255) & ~(size_t)255;
        return q;
    };
    int2*   rowptr2 = (int2*)alloc((size_t)n * 8);
    float*  dinv    = (float*)alloc((size_t)n * 4);
    int*    gcursor = (int*)alloc(NBKT * 4);
    int*    deg     = (int*)alloc((size_t)n * 4);
    int*    cur     = (int*)alloc((size_t)n * 4);
    int*    bsum    = (int*)alloc(256 * 4);
    int*    binned  = (int*)alloc((size_t)NBKT * CAP * 4);
    int*    csr     = (int*)alloc(((size_t)E + n + 256) * 4);
    __half* h1      = (__half*)alloc((size_t)n * 64 * 2);
    __half* h2      = (__half*)alloc((size_t)n * 32 * 2);

    int nchunks  = (E + CHUNK - 1) / CHUNK;           // 391
    int nbuckets = (n + BNODES - 1) / BNODES;         // 196 (<= NBKT)
    int nblk     = (n + 127) / 128;                   // 782
    int nb2      = (n + 1023) / 1024;                 // 98 scan blocks
    int npairs   = (n + 1) / 2;                       // 2 nodes per wave
    int aggblk   = (npairs + (BS / 64) - 1) / (BS / 64);

    hipMemsetAsync(gcursor, 0, NBKT * 4 + (((size_t)n * 4 + 255) & ~(size_t)255),
                   stream);  // gcursor + deg are adjacent allocations
    k_prep<<<nchunks + nblk, BS, 0, stream>>>(srcA, dstA, gcursor, binned, deg, E,
                                              x, W1, h1, n, nchunks);
    k_scan1<<<nb2, BS, 0, stream>>>(deg, bsum, n);
    k_scan2<<<nb2, BS, 0, stream>>>(deg, bsum, nb2, rowptr2, dinv, csr, cur, n);
    k_place2<<<nbuckets * PB, BS, 0, stream>>>(binned, gcursor, cur, csr);
    k_aggmm<<<aggblk, BS, 0, stream>>>(h1, csr, rowptr2, dinv, b1, W2, h2, n);
    k_agg32<<<aggblk, BS, 0, stream>>>(h2, csr, rowptr2, dinv, b2, out, n);
}

// Round 8
// 220.583 us; speedup vs baseline: 1.7758x; 1.3988x over previous
//
#include <hip/hip_runtime.h>
#include <hip/hip_fp16.h>

#define BS 256
#define BSHIFT 9                // 512 nodes per bucket
#define BNODES (1 << BSHIFT)
#define NBKT 256                // bucket table size (>= ceil(100000/512)=196); n <= 2^17
#define CAP 12288               // edge capacity per bucket (mean 8192 at E=1.6M, +45 sigma)
#define CHUNK 4096              // edges per scatter chunk (16/thread)
// packed edge word: src in bits [0,17), local dst (li) in bits [17,26)

typedef _Float16 f16x8 __attribute__((ext_vector_type(8)));
typedef float f32x4 __attribute__((ext_vector_type(4)));

// ---------------- mgemm device body: H[rows of bid] = fp16(X @ W1), unscaled ----
// dinv applied per-edge in aggmm (r4-proven). Shared by prepA/prepB.

__device__ __forceinline__ void mgemm_body(const float* __restrict__ X,
                                           const float* __restrict__ W,
                                           __half* __restrict__ H, int n, int bid,
                                           _Float16* sB) {
    constexpr int K = 128, COLS = 64;
    constexpr int KC = K / 8;
    constexpr int SWZ = 15;
    constexpr int NT = COLS / 16;
    int t = threadIdx.x;
    for (int idx = t; idx < COLS * KC; idx += BS) {
        int c = idx / KC, k8 = idx % KC;
        f16x8 v;
#pragma unroll
        for (int j = 0; j < 8; ++j) v[j] = (_Float16)W[(k8 * 8 + j) * COLS + c];
        *(f16x8*)&sB[c * K + ((k8 ^ (c & SWZ)) * 8)] = v;
    }
    __syncthreads();
    int w = t >> 6, lane = t & 63;
    int lm = lane & 15, q = lane >> 4;
    int row_m0 = bid * 128 + w * 32;
    f32x4 acc[2][NT];
#pragma unroll
    for (int tm = 0; tm < 2; ++tm)
#pragma unroll
        for (int tn = 0; tn < NT; ++tn) acc[tm][tn] = (f32x4){0.f, 0.f, 0.f, 0.f};
#pragma unroll
    for (int kk = 0; kk < K / 32; ++kk) {
        int k0 = kk * 32 + q * 8;
        f16x8 af[2], bf[NT];
#pragma unroll
        for (int tm = 0; tm < 2; ++tm) {
            int row = row_m0 + tm * 16 + lm;
            int rl = row < n ? row : (n - 1);  // clamp: in-bounds, values unused
            const float4* xp = (const float4*)X + ((size_t)rl * K + k0) / 4;
            float4 a = xp[0], b = xp[1];
            f16x8 v;
            v[0] = (_Float16)a.x; v[1] = (_Float16)a.y;
            v[2] = (_Float16)a.z; v[3] = (_Float16)a.w;
            v[4] = (_Float16)b.x; v[5] = (_Float16)b.y;
            v[6] = (_Float16)b.z; v[7] = (_Float16)b.w;
            af[tm] = v;
        }
#pragma unroll
        for (int tn = 0; tn < NT; ++tn) {
            int c = tn * 16 + lm;
            bf[tn] = *(const f16x8*)&sB[c * K + (((kk * 4 + q) ^ (c & SWZ)) * 8)];
        }
#pragma unroll
        for (int tm = 0; tm < 2; ++tm)
#pragma unroll
            for (int tn = 0; tn < NT; ++tn)
                acc[tm][tn] = __builtin_amdgcn_mfma_f32_16x16x32_f16(af[tm], bf[tn],
                                                                     acc[tm][tn], 0, 0, 0);
    }
#pragma unroll
    for (int tm = 0; tm < 2; ++tm) {
#pragma unroll
        for (int r = 0; r < 4; ++r) {
            int row = row_m0 + tm * 16 + q * 4 + r;
            if (row < n) {
#pragma unroll
                for (int tn = 0; tn < NT; ++tn) {
                    int col = tn * 16 + lm;
                    H[(size_t)row * COLS + col] = __float2half_rn(acc[tm][tn][r]);
                }
            }
        }
    }
}

// ---------------- prepA: fused [scatter || mgemm rows 0..mgA) ----------------
// r7: mgemm split across BOTH prep phases so build's idle CUs (196 blocks,
// <1/CU) also get MFMA work. r4 scatter verbatim (NO per-edge global atomics —
// r5/r6 proved those bounce lines cross-XCD at 64B/op).

__global__ __launch_bounds__(BS) void k_prepA(const int* __restrict__ src,
                                              const int* __restrict__ dst,
                                              int* __restrict__ gcursor,
                                              int* __restrict__ binned, int E,
                                              const float* __restrict__ X,
                                              const float* __restrict__ W,
                                              __half* __restrict__ H, int n,
                                              int nchunks) {
    __shared__ int sh[NBKT];
    __shared__ int sbase[NBKT];
    __shared__ __align__(16) _Float16 sB[64 * 128];
    int t = threadIdx.x;
    if (blockIdx.x < nchunks) {
        // ---- scatter path ----
        sh[t] = 0;
        __syncthreads();
        int cbase = blockIdx.x * CHUNK;
        int sv[CHUNK / BS], dv[CHUNK / BS], rv[CHUNK / BS];
#pragma unroll
        for (int j = 0; j < CHUNK / BS; ++j) {
            int e = cbase + j * BS + t;
            rv[j] = -1;
            if (e < E) {
                sv[j] = src[e];
                dv[j] = dst[e];
                rv[j] = atomicAdd(&sh[dv[j] >> BSHIFT], 1);
            }
        }
        __syncthreads();
        sbase[t] = sh[t] ? atomicAdd(&gcursor[t], sh[t]) : 0;
        __syncthreads();
#pragma unroll
        for (int j = 0; j < CHUNK / BS; ++j) {
            if (rv[j] >= 0) {
                int b = dv[j] >> BSHIFT;
                binned[(size_t)b * CAP + sbase[b] + rv[j]] =
                    sv[j] | ((dv[j] & (BNODES - 1)) << 17);
            }
        }
        return;
    }
    mgemm_body(X, W, H, n, blockIdx.x - nchunks, sB);
}

// ---------------- prepB: fused [build || mgemm rows mgA..nblk) ----------------
// build (r4-verbatim): histogram -> LDS scan -> rowptr2/dinv/self-loop -> csr.

__global__ __launch_bounds__(BS) void k_prepB(const int* __restrict__ binned,
                                              const int* __restrict__ cnts,
                                              int2* __restrict__ rowptr2,
                                              float* __restrict__ dinv,
                                              int* __restrict__ csr, int n,
                                              int nbuckets,
                                              const float* __restrict__ X,
                                              const float* __restrict__ W,
                                              __half* __restrict__ H, int mgA) {
    __shared__ int h[BNODES];
    __shared__ int rp[BNODES];
    __shared__ int cur[BNODES];
    __shared__ int ws[4];
    __shared__ __align__(16) _Float16 sB[64 * 128];
    int t = threadIdx.x;
    if (blockIdx.x >= nbuckets) {
        mgemm_body(X, W, H, n, blockIdx.x - nbuckets + mgA, sB);
        return;
    }
    int bkt = blockIdx.x;
    int node0 = bkt << BSHIFT;
    int nn = min(BNODES, n - node0);
#pragma unroll
    for (int i = t; i < BNODES; i += BS) h[i] = 0;
    __syncthreads();
    int cnt = cnts[bkt];
    const int* eb = binned + (size_t)bkt * CAP;
    for (int e = t; e < cnt; e += BS) atomicAdd(&h[eb[e] >> 17], 1);
    __syncthreads();
    int i0 = 2 * t;
    int v0 = h[i0], v1 = h[i0 + 1];
    int pair = v0 + v1;
    int lane = t & 63, w = t >> 6;
    int incl = pair;
#pragma unroll
    for (int off = 1; off < 64; off <<= 1) {
        int u = __shfl_up(incl, off);
        if (lane >= off) incl += u;
    }
    if (lane == 63) ws[w] = incl;
    __syncthreads();
    int woff = 0;
    for (int q = 0; q < w; ++q) woff += ws[q];
    int excl = woff + incl - pair;
    int cb = bkt * (CAP + BNODES);
    int r0 = cb + excl + i0;
    int r1 = r0 + v0 + 1;
    rp[i0] = r0; rp[i0 + 1] = r1;
    cur[i0] = 1; cur[i0 + 1] = 1;  // slot 0 = self-loop
    if (i0 < nn) {
        rowptr2[node0 + i0] = make_int2(r0, r1);
        dinv[node0 + i0] = rsqrtf((float)(v0 + 1));
        csr[r0] = node0 + i0;
    }
    if (i0 + 1 < nn) {
        rowptr2[node0 + i0 + 1] = make_int2(r1, r1 + v1 + 1);
        dinv[node0 + i0 + 1] = rsqrtf((float)(v1 + 1));
        csr[r1] = node0 + i0 + 1;
    }
    __syncthreads();
    for (int e = t; e < cnt; e += BS) {
        int p = eb[e];
        int li = p >> 17;
        int r = atomicAdd(&cur[li], 1);
        csr[rp[li] + r] = p & 0x1FFFF;
    }
}

// ---------------- aggmm: fused agg64 + relu(v+b1) + (u @ W2) * dinv -> h2 fp16 ------
// FROZEN (r4-proven): per-edge dinv[src] via __hfma2; lean loop. Pinned ~56us at
// the random-line fabric service floor (~1.7TB/s on 86MB; invariant r9/r13/r14/r3).

__device__ __forceinline__ void acc_fma(float4 raw, __half2 d, __half2& p0, __half2& p1,
                                        __half2& p2, __half2& p3) {
    const __half2* u = (const __half2*)&raw;
    p0 = __hfma2(u[0], d, p0); p1 = __hfma2(u[1], d, p1);
    p2 = __hfma2(u[2], d, p2); p3 = __hfma2(u[3], d, p3);
}

__global__ __launch_bounds__(BS) void k_aggmm(const __half* __restrict__ hsrc,
                                              const int* __restrict__ csr,
                                              const int2* __restrict__ rowptr2,
                                              const float* __restrict__ dinv,
                                              const float* __restrict__ b1,
                                              const float* __restrict__ W2,  // [64][32]
                                              __half* __restrict__ h2, int n) {
    __shared__ float sW2[64 * 32];            // 8 KB, layout [k][c]
    __shared__ float sB1[64];
    __shared__ float sU[(BS / 64) * 2 * 64];  // 4 waves x 2 nodes x 64 = 2 KB
    int t = threadIdx.x;
    for (int i = t; i < 64 * 32; i += BS) sW2[i] = W2[i];
    if (t < 64) sB1[t] = b1[t];
    __syncthreads();

    int npairs = (n + 1) / 2;
    int wib = t >> 6;
    int wid = blockIdx.x * (BS / 64) + wib;
    if (wid >= npairs) return;  // wave-uniform; no barriers after this point
    int lane = t & 63;
    int half = lane >> 5, hl = lane & 31;
    int node = wid * 2 + half;
    bool valid = node < n;
    int b = 0, e = 0;
    if (valid) { int2 be = rowptr2[node]; b = be.x; e = be.y; }
    int slot = hl >> 3, fq = hl & 7;  // 4 edge slots, feature octet fq*8..fq*8+8
    __half2 pA0 = __float2half2_rn(0.f), pA1 = pA0, pA2 = pA0, pA3 = pA0;
    __half2 pB0 = pA0, pB1 = pA0, pB2 = pA0, pB3 = pA0;
    for (int c = b; c < e; c += 32) {
        int m = e - c;
        if (m > 32) m = 32;
        int sv = (hl < m) ? csr[c + hl] : 0;
        float dsv = dinv[sv];  // lanes hl>=m load dinv[0]; never selected below
        int j = 0;
        for (; j + 7 < m; j += 8) {
            int s0 = __shfl(sv, j + slot, 32);
            float d0 = __shfl(dsv, j + slot, 32);
            int s1 = __shfl(sv, j + 4 + slot, 32);
            float d1 = __shfl(dsv, j + 4 + slot, 32);
            float4 r0 = *((const float4*)(hsrc + (size_t)s0 * 64) + fq);
            float4 r1 = *((const float4*)(hsrc + (size_t)s1 * 64) + fq);
            acc_fma(r0, __float2half2_rn(d0), pA0, pA1, pA2, pA3);
            acc_fma(r1, __float2half2_rn(d1), pB0, pB1, pB2, pB3);
        }
        for (; j < m; j += 4) {
            int js = j + slot;
            int s = __shfl(sv, js < m ? js : 0, 32);
            float d = __shfl(dsv, js < m ? js : 0, 32);
            if (js < m) {
                float4 r0 = *((const float4*)(hsrc + (size_t)s * 64) + fq);
                acc_fma(r0, __float2half2_rn(d), pA0, pA1, pA2, pA3);
            }
        }
    }
    // merge packed partials in fp32: 8 feature sums per lane
    float2 f0 = __half22float2(pA0), f1 = __half22float2(pA1);
    float2 f2 = __half22float2(pA2), f3 = __half22float2(pA3);
    float2 g0 = __half22float2(pB0), g1v = __half22float2(pB1);
    float2 g2 = __half22float2(pB2), g3 = __half22float2(pB3);
    float a0 = f0.x + g0.x, a1 = f0.y + g0.y, a2 = f1.x + g1v.x, a3 = f1.y + g1v.y;
    float a4 = f2.x + g2.x, a5 = f2.y + g2.y, a6 = f3.x + g3.x, a7 = f3.y + g3.y;
    // cross-slot reduction: slots {0,1,2,3} at hl = slot*8+fq
    a0 += __shfl_down(a0, 16); a1 += __shfl_down(a1, 16);
    a2 += __shfl_down(a2, 16); a3 += __shfl_down(a3, 16);
    a4 += __shfl_down(a4, 16); a5 += __shfl_down(a5, 16);
    a6 += __shfl_down(a6, 16); a7 += __shfl_down(a7, 16);
    a0 += __shfl_down(a0, 8);  a1 += __shfl_down(a1, 8);
    a2 += __shfl_down(a2, 8);  a3 += __shfl_down(a3, 8);
    a4 += __shfl_down(a4, 8);  a5 += __shfl_down(a5, 8);
    a6 += __shfl_down(a6, 8);  a7 += __shfl_down(a7, 8);

    // layer-2 input: u = relu(dinv[node] * acc + b1); lanes hl<8 own features hl*8..+8
    if (valid && hl < 8) {
        float dv = dinv[node];
        float* up = &sU[(wib * 2 + half) * 64 + hl * 8];
        up[0] = fmaxf(a0 * dv + sB1[hl * 8 + 0], 0.f);
        up[1] = fmaxf(a1 * dv + sB1[hl * 8 + 1], 0.f);
        up[2] = fmaxf(a2 * dv + sB1[hl * 8 + 2], 0.f);
        up[3] = fmaxf(a3 * dv + sB1[hl * 8 + 3], 0.f);
        up[4] = fmaxf(a4 * dv + sB1[hl * 8 + 4], 0.f);
        up[5] = fmaxf(a5 * dv + sB1[hl * 8 + 5], 0.f);
        up[6] = fmaxf(a6 * dv + sB1[hl * 8 + 6], 0.f);
        up[7] = fmaxf(a7 * dv + sB1[hl * 8 + 7], 0.f);
    }
    // in-wave matvec: lanes 0-31 -> node A cols, lanes 32-63 -> node B cols.
    int nodeSel = lane >> 5;
    int mvnode = wid * 2 + nodeSel;
    if (mvnode < n) {
        const float* u = &sU[(wib * 2 + nodeSel) * 64];
        int cc = lane & 31;
        float acc = 0.f;
#pragma unroll
        for (int k = 0; k < 64; ++k) acc = fmaf(u[k], sW2[k * 32 + cc], acc);
        h2[(size_t)mvnode * 32 + cc] = __float2half_rn(acc * dinv[mvnode]);
    }
}

// ---------------- agg32: out = dinv .* (A-gather h2) + b2 (fp32) ----------------
// 4 lanes/edge x float4 (full 64B row), 8 edge slots per half, fp32 accumulate.
// h2 rows already carry their src-side dinv (folded in aggmm's h2 write).

__global__ __launch_bounds__(BS) void k_agg32(const __half* __restrict__ h,
                                              const int* __restrict__ csr,
                                              const int2* __restrict__ rowptr2,
                                              const float* __restrict__ dinv,
                                              const float* __restrict__ bias,
                                              float* __restrict__ out, int n) {
    int wid = (blockIdx.x * BS + threadIdx.x) >> 6;
    int lane = threadIdx.x & 63;
    int half = lane >> 5, hl = lane & 31;
    int node = wid * 2 + half;
    bool valid = node < n;
    int b = 0, e = 0;
    if (valid) { int2 be = rowptr2[node]; b = be.x; e = be.y; }
    int slot = hl >> 2, fq = hl & 3;  // 8 edge slots, feature quad fq*8..fq*8+8
    float a0 = 0.f, a1 = 0.f, a2 = 0.f, a3 = 0.f;
    float a4 = 0.f, a5 = 0.f, a6 = 0.f, a7 = 0.f;
    for (int c = b; c < e; c += 32) {
        int m = e - c;
        if (m > 32) m = 32;
        int sv = (hl < m) ? csr[c + hl] : 0;
        int j = 0;
        for (; j + 15 < m; j += 16) {
            int s0 = __shfl(sv, j + slot, 32);
            int s1 = __shfl(sv, j + 8 + slot, 32);
            float4 r0 = *((const float4*)(h + (size_t)s0 * 32) + fq);
            float4 r1 = *((const float4*)(h + (size_t)s1 * 32) + fq);
            const __half2* u0 = (const __half2*)&r0;
            const __half2* u1 = (const __half2*)&r1;
            float2 q0 = __half22float2(u0[0]), q1 = __half22float2(u0[1]);
            float2 q2 = __half22float2(u0[2]), q3 = __half22float2(u0[3]);
            a0 += q0.x; a1 += q0.y; a2 += q1.x; a3 += q1.y;
            a4 += q2.x; a5 += q2.y; a6 += q3.x; a7 += q3.y;
            q0 = __half22float2(u1[0]); q1 = __half22float2(u1[1]);
            q2 = __half22float2(u1[2]); q3 = __half22float2(u1[3]);
            a0 += q0.x; a1 += q0.y; a2 += q1.x; a3 += q1.y;
            a4 += q2.x; a5 += q2.y; a6 += q3.x; a7 += q3.y;
        }
        for (; j < m; j += 8) {
            int js = j + slot;
            int s = __shfl(sv, js < m ? js : 0, 32);
            if (js < m) {
                float4 r0 = *((const float4*)(h + (size_t)s * 32) + fq);
                const __half2* u0 = (const __half2*)&r0;
                float2 q0 = __half22float2(u0[0]), q1 = __half22float2(u0[1]);
                float2 q2 = __half22float2(u0[2]), q3 = __half22float2(u0[3]);
                a0 += q0.x; a1 += q0.y; a2 += q1.x; a3 += q1.y;
                a4 += q2.x; a5 += q2.y; a6 += q3.x; a7 += q3.y;
            }
        }
    }
    // cross-slot reduction: slots {0..7} at hl = slot*4+fq
    a0 += __shfl_down(a0, 16); a1 += __shfl_down(a1, 16);
    a2 += __shfl_down(a2, 16); a3 += __shfl_down(a3, 16);
    a4 += __shfl_down(a4, 16); a5 += __shfl_down(a5, 16);
    a6 += __shfl_down(a6, 16); a7 += __shfl_down(a7, 16);
    a0 += __shfl_down(a0, 8);  a1 += __shfl_down(a1, 8);
    a2 += __shfl_down(a2, 8);  a3 += __shfl_down(a3, 8);
    a4 += __shfl_down(a4, 8);  a5 += __shfl_down(a5, 8);
    a6 += __shfl_down(a6, 8);  a7 += __shfl_down(a7, 8);
    a0 += __shfl_down(a0, 4);  a1 += __shfl_down(a1, 4);
    a2 += __shfl_down(a2, 4);  a3 += __shfl_down(a3, 4);
    a4 += __shfl_down(a4, 4);  a5 += __shfl_down(a5, 4);
    a6 += __shfl_down(a6, 4);  a7 += __shfl_down(a7, 4);
    if (valid && hl < 4) {
        float dv = dinv[node];
        const float4* bp = (const float4*)bias + hl * 2;
        float4 b0 = bp[0], b1v = bp[1];
        float4 o0 = make_float4(a0 * dv + b0.x, a1 * dv + b0.y,
                                a2 * dv + b0.z, a3 * dv + b0.w);
        float4 o1 = make_float4(a4 * dv + b1v.x, a5 * dv + b1v.y,
                                a6 * dv + b1v.z, a7 * dv + b1v.w);
        float4* op = (float4*)(out + (size_t)node * 32 + hl * 8);
        op[0] = o0; op[1] = o1;
    }
}

// ---------------- launch ----------------

extern "C" void kernel_launch(void* const* d_in, const int* in_sizes, int n_in,
                              void* d_out, int out_size, void* d_ws, size_t ws_size,
                              hipStream_t stream) {
    const float* x  = (const float*)d_in[0];
    const int* eidx = (const int*)d_in[1];
    const float* W1 = (const float*)d_in[2];
    const float* b1 = (const float*)d_in[3];
    const float* W2 = (const float*)d_in[4];
    const float* b2 = (const float*)d_in[5];
    float* out = (float*)d_out;

    int n = in_sizes[0] / 128;
    int E = in_sizes[1] / 2;
    const int* srcA = eidx;
    const int* dstA = eidx + E;

    char* p = (char*)d_ws;
    auto alloc = [&](size_t bytes) {
        char* q = p;
        p += (bytes + 255) & ~(size_t)255;
        return q;
    };
    int2*   rowptr2 = (int2*)alloc((size_t)n * 8);
    float*  dinv    = (float*)alloc((size_t)n * 4);
    int*    gcursor = (int*)alloc(NBKT * 4);
    int*    binned  = (int*)alloc((size_t)NBKT * CAP * 4);
    int*    csr     = (int*)alloc((size_t)NBKT * (CAP + BNODES) * 4);
    __half* h1      = (__half*)alloc((size_t)n * 64 * 2);
    __half* h2      = (__half*)alloc((size_t)n * 32 * 2);

    int nchunks  = (E + CHUNK - 1) / CHUNK;           // 391
    int nbuckets = (n + BNODES - 1) / BNODES;         // 196 (<= NBKT)
    int nblk     = (n + 127) / 128;                   // 782
    int mgA      = nblk / 2;                          // mgemm rows split point
    int npairs   = (n + 1) / 2;                       // 2 nodes per wave
    int aggblk   = (npairs + (BS / 64) - 1) / (BS / 64);

    hipMemsetAsync(gcursor, 0, NBKT * 4, stream);
    k_prepA<<<nchunks + mgA, BS, 0, stream>>>(srcA, dstA, gcursor, binned, E,
                                              x, W1, h1, n, nchunks);
    k_prepB<<<nbuckets + (nblk - mgA), BS, 0, stream>>>(binned, gcursor, rowptr2,
                                                        dinv, csr, n, nbuckets,
                                                        x, W1, h1, mgA);
    k_aggmm<<<aggblk, BS, 0, stream>>>(h1, csr, rowptr2, dinv, b1, W2, h2, n);
    k_agg32<<<aggblk, BS, 0, stream>>>(h2, csr, rowptr2, dinv, b2, out, n);
}